// Round 4
// baseline (495.637 us; speedup 1.0000x reference)
//
#include <hip/hip_runtime.h>

#define CN 256
#define HN 64
#define WN 64
#define NNW 32
#define HW (HN*WN)            // 4096
#define NREF (NNW*HW)         // 131072
#define KD 256

#define BM 256
#define BN 256
#define NT2 32                // B-tiles per block (each 256 refs x K=256)

using bf16x8 = __attribute__((ext_vector_type(8))) short;
using f32x4  = __attribute__((ext_vector_type(4))) float;

__device__ inline unsigned short f2bf(float x) {
  unsigned int u = __float_as_uint(x);
  return (unsigned short)((u + 0x7fffu + ((u >> 16) & 1u)) >> 16);
}

__device__ inline void atomicMaxFloat(float* addr, float val) {
  if (val >= 0.f) atomicMax(reinterpret_cast<int*>(addr), __float_as_int(val));
  else            atomicMin(reinterpret_cast<unsigned int*>(addr), __float_as_uint(val));
}

__device__ inline void gload_lds16(const void* g, void* l) {
  __builtin_amdgcn_global_load_lds(
      (const __attribute__((address_space(1))) void*)g,
      (__attribute__((address_space(3))) void*)l, 16, 0, 0);
}

// ---------------- normalize (refs blocks 0..2047, img blocks 2048..2111) ----
__global__ __launch_bounds__(256)
void norm_kernel(const float* __restrict__ refs, const float* __restrict__ img,
                 unsigned short* __restrict__ Rb, unsigned short* __restrict__ Qb,
                 float* __restrict__ out) {
  __shared__ float tile[CN][WN + 1];
  __shared__ float ssq[4][WN];
  __shared__ float scl[WN];
  const int bid = blockIdx.x;
  const int t = threadIdx.x;
  const float* src; unsigned short* dst; int nh;
  if (bid < NNW * HN) { src = refs; dst = Rb; nh = bid; }
  else {
    src = img; dst = Qb; nh = bid - NNW * HN;
    if (t < 64) out[(size_t)nh * 64 + t] = -INFINITY;   // init output
  }
  const float* base = src + (size_t)(nh >> 6) * (CN * (size_t)HW) + (size_t)(nh & 63) * WN;

  const int c16 = t >> 4, w4 = (t & 15) * 4;
#pragma unroll
  for (int j = 0; j < 16; ++j) {
    int c = j * 16 + c16;
    float4 v = *(const float4*)&base[(size_t)c * HW + w4];
    tile[c][w4 + 0] = v.x; tile[c][w4 + 1] = v.y;
    tile[c][w4 + 2] = v.z; tile[c][w4 + 3] = v.w;
  }
  __syncthreads();
  {
    int w = t & 63, vv = t >> 6;
    float s = 0.f;
#pragma unroll 8
    for (int cc = 0; cc < 64; ++cc) { float x = tile[vv * 64 + cc][w]; s += x * x; }
    ssq[vv][w] = s;
  }
  __syncthreads();
  if (t < 64)
    scl[t] = 1.f / fmaxf(sqrtf(ssq[0][t] + ssq[1][t] + ssq[2][t] + ssq[3][t]), 1e-12f);
  __syncthreads();
  const int w = t >> 2, cq = t & 3;
  unsigned short* orow = dst + ((size_t)nh * WN + w) * KD;
  const float sc = scl[w];
#pragma unroll
  for (int j = 0; j < 8; ++j) {
    int c0 = (j * 4 + cq) * 8;
    bf16x8 o;
#pragma unroll
    for (int k = 0; k < 8; ++k) o[k] = (short)f2bf(tile[c0 + k][w] * sc);
    *(bf16x8*)&orow[c0] = o;
  }
}

// ------- GEMM-max, 256x256 tile, merged phases + register-prefetch pipeline -
#define BARR() __builtin_amdgcn_s_barrier()
#define SCHED0() __builtin_amdgcn_sched_barrier(0)
#define GATE(N) asm volatile("s_waitcnt vmcnt(" #N ")" ::: "memory")

// prefetch one sub-buffer's fragments (8 A + 4 B) into a register set
#define DSR2(SUB, AR, BR) do { \
  _Pragma("unroll") \
  for (int ni = 0; ni < 4; ++ni) \
    BR[ni] = *(const bf16x8*)&ldsB[(SUB)*8192 + boff + (ni*16)*32]; \
  _Pragma("unroll") \
  for (int mi = 0; mi < 4; ++mi) { \
    AR[mi]     = *(const bf16x8*)&ldsA[(SUB)*8192 + aoff + (mi*16)*32]; \
    AR[4 + mi] = *(const bf16x8*)&ldsA[(SUB)*8192 + aoff + ((64 + mi*16))*32]; \
  } \
} while (0)

#define MFMA2(AR, BR) do { \
  __builtin_amdgcn_s_setprio(1); \
  _Pragma("unroll") \
  for (int mh = 0; mh < 2; ++mh) \
  _Pragma("unroll") \
  for (int mi = 0; mi < 4; ++mi) \
  _Pragma("unroll") \
  for (int ni = 0; ni < 4; ++ni) \
    acc[mh][mi][ni] = __builtin_amdgcn_mfma_f32_16x16x32_bf16(AR[mh*4+mi], BR[ni], acc[mh][mi][ni], 0, 0, 0); \
  __builtin_amdgcn_s_setprio(0); \
} while (0)

#define MFMA2Z(AR, BR) do { \
  __builtin_amdgcn_s_setprio(1); \
  _Pragma("unroll") \
  for (int mh = 0; mh < 2; ++mh) \
  _Pragma("unroll") \
  for (int mi = 0; mi < 4; ++mi) \
  _Pragma("unroll") \
  for (int ni = 0; ni < 4; ++ni) \
    acc[mh][mi][ni] = __builtin_amdgcn_mfma_f32_16x16x32_bf16(AR[mh*4+mi], BR[ni], ZZ, 0, 0, 0); \
  __builtin_amdgcn_s_setprio(0); \
} while (0)

#define STG_A2(SUB, QOFF) do { \
  gload_lds16(qsrc0 + (QOFF),            &ldsA[(SUB)*8192 + wid*512]); \
  gload_lds16(qsrc0 + 128*KD + (QOFF),   &ldsA[(SUB)*8192 + (wid+8)*512]); \
} while (0)

#define STG_B2(SUB, PTR, BOFF) do { \
  gload_lds16((PTR) + (BOFF),            &ldsB[(SUB)*8192 + wid*512]); \
  gload_lds16((PTR) + (BOFF) + 128*KD,   &ldsB[(SUB)*8192 + (wid+8)*512]); \
} while (0)

// steady phase: stage SSUB, gate 2-phase-old stage, prefetch PFSUB -> (AN,BN),
// MFMA on (AC,BC) prefetched last phase
#define PHX(SSUB, KA, BPTR, KB, PFSUB, AN, BN_, AC, BC, MF) do { \
  STG_A2(SSUB, KA); STG_B2(SSUB, BPTR, KB); \
  GATE(8); BARR(); SCHED0(); \
  DSR2(PFSUB, AN, BN_); \
  MF(AC, BC); \
  BARR(); \
} while (0)

#define FOLD2() do { \
  _Pragma("unroll") \
  for (int mh = 0; mh < 2; ++mh) \
  _Pragma("unroll") \
  for (int mi = 0; mi < 4; ++mi) \
  _Pragma("unroll") \
  for (int ee = 0; ee < 4; ++ee) { \
    float v0 = fmaxf(acc[mh][mi][0][ee], acc[mh][mi][1][ee]); \
    float v1 = fmaxf(acc[mh][mi][2][ee], acc[mh][mi][3][ee]); \
    run[mh][mi][ee] = fmaxf(run[mh][mi][ee], fmaxf(v0, v1)); \
  } \
} while (0)

__global__ __launch_bounds__(512, 2)
void simmax_kernel(const unsigned short* __restrict__ Q,
                   const unsigned short* __restrict__ R,
                   float* __restrict__ out) {
  // LDS: sub-buffer s, each 256 rows x 32 k bf16 = 16KB
  __shared__ unsigned short ldsA[4 * 8192];
  __shared__ unsigned short ldsB[4 * 8192];

  const int t = threadIdx.x;
  const int lane = t & 63;
  const int wid = t >> 6;        // 0..7
  const int wm = wid >> 2;       // 0..1
  const int wn = wid & 3;        // 0..3

  const int id = blockIdx.x;
  const int bm  = id >> 4;       // 0..15
  const int nch = id & 15;       // same id%8 -> same XCD neighborhood

  // staging: lane covers row lane>>2 of 16-row group, phys chunk lane&3,
  // pre-swizzled source chunk = (lane&3) ^ ((lane>>3)&3)
  const int stg_r = wid * 16 + (lane >> 2);
  const int stg_c = ((lane & 3) ^ ((lane >> 3) & 3)) * 8;
  const unsigned short* qsrc0 = Q + (size_t)(bm * BM + stg_r) * KD + stg_c;
  const unsigned short* rsrc0 = R + (size_t)((size_t)nch * NT2 * BN + stg_r) * KD + stg_c;

  // read: phys chunk = (lane>>4) ^ ((row>>1)&3)
  const int rA0 = wm * 128 + (lane & 15);
  const int rB0 = wn * 64 + (lane & 15);
  const int aoff = rA0 * 32 + (((lane >> 4) ^ ((rA0 >> 1) & 3)) * 8);
  const int boff = rB0 * 32 + (((lane >> 4) ^ ((rB0 >> 1) & 3)) * 8);

  const f32x4 ZZ = {0.f, 0.f, 0.f, 0.f};
  f32x4 acc[2][4][4];
  f32x4 run[2][4];
#pragma unroll
  for (int mh = 0; mh < 2; ++mh)
#pragma unroll
    for (int mi = 0; mi < 4; ++mi)
#pragma unroll
      for (int ee = 0; ee < 4; ++ee) run[mh][mi][ee] = -1e30f;

  // double-buffered fragment sets (must live across loop iterations)
  bf16x8 a0[8], b0[4], a1[8], b1[4];

  // prologue: stage sub0(k0), sub1(k32), sub2(k64); prime set0 <- sub0
  STG_A2(0, 0);  STG_B2(0, rsrc0, 0);
  STG_A2(1, 32); STG_B2(1, rsrc0, 32);
  STG_A2(2, 64); STG_B2(2, rsrc0, 64);
  GATE(8); BARR(); SCHED0();
  DSR2(0, a0, b0);

  const unsigned short* rs = rsrc0;
  for (int bt = 0; bt < NT2 - 1; ++bt) {
    //  SSUB KA    BPTR KB          PF  AN  BN  AC  BC
    PHX(3,  96,  rs,  96,          1, a1, b1, a0, b0, MFMA2Z);  // m0: k0
    PHX(0,  128, rs,  128,         2, a0, b0, a1, b1, MFMA2);   // m1: k32
    PHX(1,  160, rs,  160,         3, a1, b1, a0, b0, MFMA2);   // m2: k64
    PHX(2,  192, rs,  192,         0, a0, b0, a1, b1, MFMA2);   // m3: k96
    PHX(3,  224, rs,  224,         1, a1, b1, a0, b0, MFMA2);   // m4: k128
    PHX(0,  0,   rs,  65536,       2, a0, b0, a1, b1, MFMA2);   // m5: k160
    PHX(1,  32,  rs,  65536 + 32,  3, a1, b1, a0, b0, MFMA2);   // m6: k192
    PHX(2,  64,  rs,  65536 + 64,  0, a0, b0, a1, b1, MFMA2);   // m7: k224
    FOLD2();
    rs += 65536;
  }

  // epilogue B-tile (bt = NT2-1): stages stop after m4; draining gates
  {
    PHX(3,  96,  rs,  96,  1, a1, b1, a0, b0, MFMA2Z);  // m0
    PHX(0,  128, rs,  128, 2, a0, b0, a1, b1, MFMA2);   // m1
    PHX(1,  160, rs,  160, 3, a1, b1, a0, b0, MFMA2);   // m2
    PHX(2,  192, rs,  192, 0, a0, b0, a1, b1, MFMA2);   // m3
    PHX(3,  224, rs,  224, 1, a1, b1, a0, b0, MFMA2);   // m4
    // m5: no stage; prefetch sub2 (staged m3) -> GATE(4)
    GATE(4); BARR(); SCHED0();
    DSR2(2, a0, b0);
    MFMA2(a1, b1);
    BARR();
    // m6: prefetch sub3 (staged m4) -> GATE(0)
    GATE(0); BARR(); SCHED0();
    DSR2(3, a1, b1);
    MFMA2(a0, b0);
    BARR();
    // m7
    MFMA2(a1, b1);
    FOLD2();
  }

  // reduce over the 16 column-lanes, one atomic per output row
#pragma unroll
  for (int mh = 0; mh < 2; ++mh)
#pragma unroll
  for (int mi = 0; mi < 4; ++mi)
#pragma unroll
  for (int ee = 0; ee < 4; ++ee) {
    float v = run[mh][mi][ee];
    v = fmaxf(v, __shfl_xor(v, 1));
    v = fmaxf(v, __shfl_xor(v, 2));
    v = fmaxf(v, __shfl_xor(v, 4));
    v = fmaxf(v, __shfl_xor(v, 8));
    if ((lane & 15) == 0)
      atomicMaxFloat(&out[bm * BM + wm * 128 + mh * 64 + mi * 16 + (lane >> 4) * 4 + ee], v);
  }
}

extern "C" void kernel_launch(void* const* d_in, const int* in_sizes, int n_in,
                              void* d_out, int out_size, void* d_ws, size_t ws_size,
                              hipStream_t stream) {
  const float* refs = (const float*)d_in[0];
  const float* img  = (const float*)d_in[1];
  float* out = (float*)d_out;

  unsigned short* Rb = (unsigned short*)d_ws;                 // 131072*256 bf16 = 64MB
  unsigned short* Qb = Rb + (size_t)NREF * KD;                // 4096*256 bf16 = 2MB

  hipLaunchKernelGGL(norm_kernel, dim3(NNW * HN + HN), dim3(256), 0, stream,
                     refs, img, Rb, Qb, out);
  hipLaunchKernelGGL(simmax_kernel, dim3(256), dim3(512), 0, stream, Qb, Rb, out);
}

// Round 5
// 292.704 us; speedup vs baseline: 1.6933x; 1.6933x over previous
//
#include <hip/hip_runtime.h>

#define CN 256
#define HN 64
#define WN 64
#define NNW 32
#define HW (HN*WN)            // 4096
#define NREF (NNW*HW)         // 131072
#define KD 256

#define BM 256
#define BN 256
#define NT2 32                // B-tiles per block (each 256 refs x K=256)

using bf16x8 = __attribute__((ext_vector_type(8))) short;
using f32x4  = __attribute__((ext_vector_type(4))) float;

__device__ inline unsigned short f2bf(float x) {
  unsigned int u = __float_as_uint(x);
  return (unsigned short)((u + 0x7fffu + ((u >> 16) & 1u)) >> 16);
}

__device__ inline void atomicMaxFloat(float* addr, float val) {
  if (val >= 0.f) atomicMax(reinterpret_cast<int*>(addr), __float_as_int(val));
  else            atomicMin(reinterpret_cast<unsigned int*>(addr), __float_as_uint(val));
}

__device__ inline void gload_lds16(const void* g, void* l) {
  __builtin_amdgcn_global_load_lds(
      (const __attribute__((address_space(1))) void*)g,
      (__attribute__((address_space(3))) void*)l, 16, 0, 0);
}

// ---------------- normalize (refs blocks 0..2047, img blocks 2048..2111) ----
__global__ __launch_bounds__(256)
void norm_kernel(const float* __restrict__ refs, const float* __restrict__ img,
                 unsigned short* __restrict__ Rb, unsigned short* __restrict__ Qb,
                 float* __restrict__ out) {
  __shared__ float tile[CN][WN + 1];
  __shared__ float ssq[4][WN];
  __shared__ float scl[WN];
  const int bid = blockIdx.x;
  const int t = threadIdx.x;
  const float* src; unsigned short* dst; int nh;
  if (bid < NNW * HN) { src = refs; dst = Rb; nh = bid; }
  else {
    src = img; dst = Qb; nh = bid - NNW * HN;
    if (t < 64) out[(size_t)nh * 64 + t] = -INFINITY;   // init output
  }
  const float* base = src + (size_t)(nh >> 6) * (CN * (size_t)HW) + (size_t)(nh & 63) * WN;

  const int c16 = t >> 4, w4 = (t & 15) * 4;
#pragma unroll
  for (int j = 0; j < 16; ++j) {
    int c = j * 16 + c16;
    float4 v = *(const float4*)&base[(size_t)c * HW + w4];
    tile[c][w4 + 0] = v.x; tile[c][w4 + 1] = v.y;
    tile[c][w4 + 2] = v.z; tile[c][w4 + 3] = v.w;
  }
  __syncthreads();
  {
    int w = t & 63, vv = t >> 6;
    float s = 0.f;
#pragma unroll 8
    for (int cc = 0; cc < 64; ++cc) { float x = tile[vv * 64 + cc][w]; s += x * x; }
    ssq[vv][w] = s;
  }
  __syncthreads();
  if (t < 64)
    scl[t] = 1.f / fmaxf(sqrtf(ssq[0][t] + ssq[1][t] + ssq[2][t] + ssq[3][t]), 1e-12f);
  __syncthreads();
  const int w = t >> 2, cq = t & 3;
  unsigned short* orow = dst + ((size_t)nh * WN + w) * KD;
  const float sc = scl[w];
#pragma unroll
  for (int j = 0; j < 8; ++j) {
    int c0 = (j * 4 + cq) * 8;
    bf16x8 o;
#pragma unroll
    for (int k = 0; k < 8; ++k) o[k] = (short)f2bf(tile[c0 + k][w] * sc);
    *(bf16x8*)&orow[c0] = o;
  }
}

// ------ GEMM-max, 256x256 tile, merged phases, compiler-counted lgkm overlap
#define BARR() __builtin_amdgcn_s_barrier()
#define SCHED0() __builtin_amdgcn_sched_barrier(0)
#define GATE(N) asm volatile("s_waitcnt vmcnt(" #N ")" ::: "memory")

#define LDA_(SUB, MI, MH) (*(const bf16x8*)&ldsA[(SUB)*8192 + aoff + ((MH)*64 + (MI)*16)*32])
#define LDB_(SUB, NI)     (*(const bf16x8*)&ldsB[(SUB)*8192 + boff + ((NI)*16)*32])

#define STG_A2(SUB, QOFF) do { \
  gload_lds16(qsrc0 + (QOFF),            &ldsA[(SUB)*8192 + wid*512]); \
  gload_lds16(qsrc0 + 128*KD + (QOFF),   &ldsA[(SUB)*8192 + (wid+8)*512]); \
} while (0)

#define STG_B2(SUB, BOFF) do { \
  gload_lds16(rs + (BOFF),               &ldsB[(SUB)*8192 + wid*512]); \
  gload_lds16(rs + (BOFF) + 128*KD,      &ldsB[(SUB)*8192 + (wid+8)*512]); \
} while (0)

// steady phase: stage SSUB; gate (forces NSUB's 2-phase-old loads); barrier
// publishes; read A(CSUB) around the mh0 MFMA half; prefetch B(NSUB) -> BNX
// under the MFMA window; BC was prefetched last phase. ACM=1 accumulates.
#define PHASE(SSUB, KA, KB, CSUB, NSUB, BC, BNX, ACM) do { \
  STG_A2(SSUB, KA); STG_B2(SSUB, KB); \
  GATE(8); BARR(); SCHED0(); \
  _Pragma("unroll") \
  for (int mi = 0; mi < 4; ++mi) a[mi] = LDA_(CSUB, mi, 0); \
  _Pragma("unroll") \
  for (int ni = 0; ni < 4; ++ni) BNX[ni] = LDB_(NSUB, ni); \
  __builtin_amdgcn_s_setprio(1); \
  _Pragma("unroll") \
  for (int mi = 0; mi < 4; ++mi) \
  _Pragma("unroll") \
  for (int ni = 0; ni < 4; ++ni) \
    acc[0][mi][ni] = __builtin_amdgcn_mfma_f32_16x16x32_bf16(a[mi], BC[ni], (ACM) ? acc[0][mi][ni] : ZZ, 0, 0, 0); \
  __builtin_amdgcn_s_setprio(0); \
  _Pragma("unroll") \
  for (int mi = 0; mi < 4; ++mi) a[4 + mi] = LDA_(CSUB, mi, 1); \
  __builtin_amdgcn_s_setprio(1); \
  _Pragma("unroll") \
  for (int mi = 0; mi < 4; ++mi) \
  _Pragma("unroll") \
  for (int ni = 0; ni < 4; ++ni) \
    acc[1][mi][ni] = __builtin_amdgcn_mfma_f32_16x16x32_bf16(a[4 + mi], BC[ni], (ACM) ? acc[1][mi][ni] : ZZ, 0, 0, 0); \
  __builtin_amdgcn_s_setprio(0); \
  SCHED0(); BARR(); \
} while (0)

// tail phase: no staging; GATE per argument; no closing barrier needed
#define MFMA_HALF(MH, AOFFS, BC) do { \
  __builtin_amdgcn_s_setprio(1); \
  _Pragma("unroll") \
  for (int mi = 0; mi < 4; ++mi) \
  _Pragma("unroll") \
  for (int ni = 0; ni < 4; ++ni) \
    acc[MH][mi][ni] = __builtin_amdgcn_mfma_f32_16x16x32_bf16(a[(AOFFS) + mi], BC[ni], acc[MH][mi][ni], 0, 0, 0); \
  __builtin_amdgcn_s_setprio(0); \
} while (0)

#define FOLD2() do { \
  _Pragma("unroll") \
  for (int mh = 0; mh < 2; ++mh) \
  _Pragma("unroll") \
  for (int mi = 0; mi < 4; ++mi) \
  _Pragma("unroll") \
  for (int ee = 0; ee < 4; ++ee) { \
    float v0 = fmaxf(acc[mh][mi][0][ee], acc[mh][mi][1][ee]); \
    float v1 = fmaxf(acc[mh][mi][2][ee], acc[mh][mi][3][ee]); \
    run[mh][mi][ee] = fmaxf(run[mh][mi][ee], fmaxf(v0, v1)); \
  } \
} while (0)

__global__ __launch_bounds__(512, 2)
void simmax_kernel(const unsigned short* __restrict__ Q,
                   const unsigned short* __restrict__ R,
                   float* __restrict__ out) {
  // LDS: 4 sub-buffers per operand, each 256 rows x 32 k bf16 = 16KB
  __shared__ unsigned short ldsA[4 * 8192];
  __shared__ unsigned short ldsB[4 * 8192];

  const int t = threadIdx.x;
  const int lane = t & 63;
  const int wid = t >> 6;        // 0..7
  const int wm = wid >> 2;       // 0..1
  const int wn = wid & 3;        // 0..3

  const int id = blockIdx.x;
  const int bm  = id >> 4;       // 0..15
  const int nch = id & 15;       // same id%8 -> same XCD neighborhood

  // staging: lane covers row lane>>2 of its 16-row group, phys chunk lane&3,
  // pre-swizzled source chunk = (lane&3) ^ ((lane>>3)&3)
  const int stg_r = wid * 16 + (lane >> 2);
  const int stg_c = ((lane & 3) ^ ((lane >> 3) & 3)) * 8;
  const unsigned short* qsrc0 = Q + (size_t)(bm * BM + stg_r) * KD + stg_c;
  const unsigned short* rsrc0 = R + (size_t)((size_t)nch * NT2 * BN + stg_r) * KD + stg_c;

  // read: phys chunk = (lane>>4) ^ ((row>>1)&3)
  const int rA0 = wm * 128 + (lane & 15);
  const int rB0 = wn * 64 + (lane & 15);
  const int aoff = rA0 * 32 + (((lane >> 4) ^ ((rA0 >> 1) & 3)) * 8);
  const int boff = rB0 * 32 + (((lane >> 4) ^ ((rB0 >> 1) & 3)) * 8);

  const f32x4 ZZ = {0.f, 0.f, 0.f, 0.f};
  f32x4 acc[2][4][4];
  f32x4 run[2][4];
#pragma unroll
  for (int mh = 0; mh < 2; ++mh)
#pragma unroll
    for (int mi = 0; mi < 4; ++mi)
#pragma unroll
      for (int ee = 0; ee < 4; ++ee) run[mh][mi][ee] = -1e30f;

  bf16x8 a[8], bA[4], bB[4];

  const unsigned short* rs = rsrc0;

  // prologue: stage sub0(k0), sub1(k32), sub2(k64); prime bA <- B(sub0)
  STG_A2(0, 0);  STG_B2(0, 0);
  STG_A2(1, 32); STG_B2(1, 32);
  STG_A2(2, 64); STG_B2(2, 64);
  GATE(8); BARR(); SCHED0();
#pragma unroll
  for (int ni = 0; ni < 4; ++ni) bA[ni] = LDB_(0, ni);

  for (int bt = 0; bt < NT2 - 1; ++bt) {
    //    SSUB  KA   KB          CSUB NSUB BC  BNX ACM
    PHASE(3,   96,  96,          0,  1,  bA, bB, 0);   // m0: k0
    PHASE(0,  128, 128,          1,  2,  bB, bA, 1);   // m1: k32
    PHASE(1,  160, 160,          2,  3,  bA, bB, 1);   // m2: k64
    PHASE(2,  192, 192,          3,  0,  bB, bA, 1);   // m3: k96
    PHASE(3,  224, 224,          0,  1,  bA, bB, 1);   // m4: k128
    PHASE(0,    0, 65536,        1,  2,  bB, bA, 1);   // m5: k160 (stages next-tile k0)
    PHASE(1,   32, 65536 + 32,   2,  3,  bA, bB, 1);   // m6: k192
    PHASE(2,   64, 65536 + 64,   3,  0,  bB, bA, 1);   // m7: k224 (prefetch next-tile B sub0)
    FOLD2();
    rs += 65536;
  }

  // epilogue B-tile: m0-m4 same as steady; m5-m7 drain without staging
  {
    PHASE(3,   96,  96,  0, 1, bA, bB, 0);   // m0
    PHASE(0,  128, 128,  1, 2, bB, bA, 1);   // m1
    PHASE(1,  160, 160,  2, 3, bA, bB, 1);   // m2
    PHASE(2,  192, 192,  3, 0, bB, bA, 1);   // m3
    PHASE(3,  224, 224,  0, 1, bA, bB, 1);   // m4
    // m5: reads sub1 (staged m2, forced by m4's GATE(8)); prefetch sub2 (staged m3)
    GATE(4); BARR(); SCHED0();
#pragma unroll
    for (int mi = 0; mi < 4; ++mi) a[mi] = LDA_(1, mi, 0);
#pragma unroll
    for (int ni = 0; ni < 4; ++ni) bA[ni] = LDB_(2, ni);
    MFMA_HALF(0, 0, bB);
#pragma unroll
    for (int mi = 0; mi < 4; ++mi) a[4 + mi] = LDA_(1, mi, 1);
    MFMA_HALF(1, 4, bB);
    // m6: reads sub2; prefetch sub3 (staged m4 -> GATE(0)); publish via barrier
    GATE(0); BARR(); SCHED0();
#pragma unroll
    for (int mi = 0; mi < 4; ++mi) a[mi] = LDA_(2, mi, 0);
#pragma unroll
    for (int ni = 0; ni < 4; ++ni) bB[ni] = LDB_(3, ni);
    MFMA_HALF(0, 0, bA);
#pragma unroll
    for (int mi = 0; mi < 4; ++mi) a[4 + mi] = LDA_(2, mi, 1);
    MFMA_HALF(1, 4, bA);
    // m7: reads sub3 (published at m6's barrier)
#pragma unroll
    for (int mi = 0; mi < 4; ++mi) a[mi] = LDA_(3, mi, 0);
    MFMA_HALF(0, 0, bB);
#pragma unroll
    for (int mi = 0; mi < 4; ++mi) a[4 + mi] = LDA_(3, mi, 1);
    MFMA_HALF(1, 4, bB);
    FOLD2();
  }

  // reduce over the 16 column-lanes, one atomic per output row
#pragma unroll
  for (int mh = 0; mh < 2; ++mh)
#pragma unroll
  for (int mi = 0; mi < 4; ++mi)
#pragma unroll
  for (int ee = 0; ee < 4; ++ee) {
    float v = run[mh][mi][ee];
    v = fmaxf(v, __shfl_xor(v, 1));
    v = fmaxf(v, __shfl_xor(v, 2));
    v = fmaxf(v, __shfl_xor(v, 4));
    v = fmaxf(v, __shfl_xor(v, 8));
    if ((lane & 15) == 0)
      atomicMaxFloat(&out[bm * BM + wm * 128 + mh * 64 + mi * 16 + (lane >> 4) * 4 + ee], v);
  }
}

extern "C" void kernel_launch(void* const* d_in, const int* in_sizes, int n_in,
                              void* d_out, int out_size, void* d_ws, size_t ws_size,
                              hipStream_t stream) {
  const float* refs = (const float*)d_in[0];
  const float* img  = (const float*)d_in[1];
  float* out = (float*)d_out;

  unsigned short* Rb = (unsigned short*)d_ws;                 // 131072*256 bf16 = 64MB
  unsigned short* Qb = Rb + (size_t)NREF * KD;                // 4096*256 bf16 = 2MB

  hipLaunchKernelGGL(norm_kernel, dim3(NNW * HN + HN), dim3(256), 0, stream,
                     refs, img, Rb, Qb, out);
  hipLaunchKernelGGL(simmax_kernel, dim3(256), dim3(512), 0, stream, Qb, Rb, out);
}

// Round 7
// 247.101 us; speedup vs baseline: 2.0058x; 1.1846x over previous
//
#include <hip/hip_runtime.h>

#define CN 256
#define HN 64
#define WN 64
#define NNW 32
#define HW (HN*WN)            // 4096
#define NREF (NNW*HW)         // 131072
#define KD 256

#define BM2 128               // block M-tile
#define BN2 128               // block N-tile
#define NCH 32                // n-chunks
#define NTILES (NREF/NCH/BN2) // 32 B-tiles per block

using bf16x8 = __attribute__((ext_vector_type(8))) short;
using f32x4  = __attribute__((ext_vector_type(4))) float;

__device__ inline unsigned short f2bf(float x) {
  unsigned int u = __float_as_uint(x);
  return (unsigned short)((u + 0x7fffu + ((u >> 16) & 1u)) >> 16);
}

__device__ inline void atomicMaxFloat(float* addr, float val) {
  if (val >= 0.f) atomicMax(reinterpret_cast<int*>(addr), __float_as_int(val));
  else            atomicMin(reinterpret_cast<unsigned int*>(addr), __float_as_uint(val));
}

__device__ inline void gload_lds16(const void* g, void* l) {
  __builtin_amdgcn_global_load_lds(
      (const __attribute__((address_space(1))) void*)g,
      (__attribute__((address_space(3))) void*)l, 16, 0, 0);
}

// ---------------- normalize (refs blocks 0..2047, img blocks 2048..2111) ----
__global__ __launch_bounds__(256)
void norm_kernel(const float* __restrict__ refs, const float* __restrict__ img,
                 unsigned short* __restrict__ Rb, unsigned short* __restrict__ Qb,
                 float* __restrict__ out) {
  __shared__ float tile[CN][WN + 1];
  __shared__ float ssq[4][WN];
  __shared__ float scl[WN];
  const int bid = blockIdx.x;
  const int t = threadIdx.x;
  const float* src; unsigned short* dst; int nh;
  if (bid < NNW * HN) { src = refs; dst = Rb; nh = bid; }
  else {
    src = img; dst = Qb; nh = bid - NNW * HN;
    if (t < 64) out[(size_t)nh * 64 + t] = -INFINITY;   // init output
  }
  const float* base = src + (size_t)(nh >> 6) * (CN * (size_t)HW) + (size_t)(nh & 63) * WN;

  const int c16 = t >> 4, w4 = (t & 15) * 4;
#pragma unroll
  for (int j = 0; j < 16; ++j) {
    int c = j * 16 + c16;
    float4 v = *(const float4*)&base[(size_t)c * HW + w4];
    tile[c][w4 + 0] = v.x; tile[c][w4 + 1] = v.y;
    tile[c][w4 + 2] = v.z; tile[c][w4 + 3] = v.w;
  }
  __syncthreads();
  {
    int w = t & 63, vv = t >> 6;
    float s = 0.f;
#pragma unroll 8
    for (int cc = 0; cc < 64; ++cc) { float x = tile[vv * 64 + cc][w]; s += x * x; }
    ssq[vv][w] = s;
  }
  __syncthreads();
  if (t < 64)
    scl[t] = 1.f / fmaxf(sqrtf(ssq[0][t] + ssq[1][t] + ssq[2][t] + ssq[3][t]), 1e-12f);
  __syncthreads();
  const int w = t >> 2, cq = t & 3;
  unsigned short* orow = dst + ((size_t)nh * WN + w) * KD;
  const float sc = scl[w];
#pragma unroll
  for (int j = 0; j < 8; ++j) {
    int c0 = (j * 4 + cq) * 8;
    bf16x8 o;
#pragma unroll
    for (int k = 0; k < 8; ++k) o[k] = (short)f2bf(tile[c0 + k][w] * sc);
    *(bf16x8*)&orow[c0] = o;
  }
}

// ---- GEMM-max: A (queries) resident in registers, B streamed via LDS ring --
#define BARR() __builtin_amdgcn_s_barrier()
#define SCHED0() __builtin_amdgcn_sched_barrier(0)
#define GATE(N) asm volatile("s_waitcnt vmcnt(" #N ")" ::: "memory")
#define LGKM0() asm volatile("s_waitcnt lgkmcnt(0)" ::: "memory")

// stage one 16KB sub-buffer (128 rows x 64 k): 4 gloads/thread, wave w rows [w*32,w*32+32)
#define STG4(SUB, PTR, KOFF) do { \
  _Pragma("unroll") \
  for (int p = 0; p < 4; ++p) \
    gload_lds16((PTR) + (KOFF) + p * 8 * KD, &lds[SUB][(w * 32 + p * 8) * 64]); \
} while (0)

// one phase: consume sub CSUB (64 k), optionally stage SSUB <- rs+KOFF
// NOTE: ks=1 must chain onto ks=0 even when ACM=0 -> ((ACM) || ks)
#define PH(CSUB, ACM, DOSTG, SSUB, KOFF, GN) do { \
  if (DOSTG) STG4(SSUB, rs, KOFF); \
  GATE(GN); BARR(); SCHED0(); \
  bf16x8 bb[2][4]; \
  _Pragma("unroll") \
  for (int ks = 0; ks < 2; ++ks) \
  _Pragma("unroll") \
  for (int ni = 0; ni < 4; ++ni) \
    bb[ks][ni] = *(const bf16x8*)&lds[CSUB][(nrow + ni * 16) * 64 + (ks ? (pk0 ^ 32) : pk0)]; \
  __builtin_amdgcn_s_setprio(1); \
  _Pragma("unroll") \
  for (int ks = 0; ks < 2; ++ks) \
  _Pragma("unroll") \
  for (int mi = 0; mi < 4; ++mi) \
  _Pragma("unroll") \
  for (int ni = 0; ni < 4; ++ni) \
    acc[mi][ni] = __builtin_amdgcn_mfma_f32_16x16x32_bf16(a[mi][(CSUB)*2 + ks], bb[ks][ni], ((ACM) || ks) ? acc[mi][ni] : ZZ, 0, 0, 0); \
  __builtin_amdgcn_s_setprio(0); \
  SCHED0(); BARR(); \
} while (0)

#define FOLD() do { \
  _Pragma("unroll") \
  for (int mi = 0; mi < 4; ++mi) \
  _Pragma("unroll") \
  for (int ee = 0; ee < 4; ++ee) { \
    float v0 = fmaxf(acc[mi][0][ee], acc[mi][1][ee]); \
    float v1 = fmaxf(acc[mi][2][ee], acc[mi][3][ee]); \
    run[mi][ee] = fmaxf(run[mi][ee], fmaxf(v0, v1)); \
  } \
} while (0)

__global__ __launch_bounds__(256, 2)
void simmax_kernel(const unsigned short* __restrict__ Q,
                   const unsigned short* __restrict__ R,
                   float* __restrict__ out) {
  // 4 ring sub-buffers: [128 rows][64 k] bf16, XOR-swizzled chunks. 64 KB total.
  __shared__ unsigned short lds[4][8192];

  const int t = threadIdx.x;
  const int lane = t & 63;
  const int w  = t >> 6;        // 0..3
  const int wm = w >> 1;        // 0..1
  const int wn = w & 1;         // 0..1

  // bijective XCD swizzle: XCD x hosts wg in [x*128, x*128+128) -> 4 n-chunks
  const int wg  = (blockIdx.x & 7) * 128 + (blockIdx.x >> 3);
  const int nch = wg >> 5;      // 0..31
  const int bm  = wg & 31;      // 0..31

  // staging lane geometry: row-in-8 = lane>>3, phys chunk lane&7,
  // pre-swizzled source chunk = (lane&7) ^ (lane>>3)
  const int srow = lane >> 3;
  const int schunk = (lane & 7) ^ srow;
  const unsigned short* qsrcA = Q + (size_t)(bm * BM2 + w * 32 + srow) * KD + schunk * 8;
  const unsigned short* rsrc0 = R + (size_t)((size_t)nch * (NTILES * BN2) + w * 32 + srow) * KD + schunk * 8;

  // read geometry: phys chunk = (ks*4 + (lane>>4)) ^ (lane&7)
  const int pk0 = (((lane >> 4) ^ (lane & 7))) * 8;   // ks=0 chunk (shorts)
  const int mrow = wm * 64 + (lane & 15);
  const int nrow = wn * 64 + (lane & 15);

  const f32x4 ZZ = {0.f, 0.f, 0.f, 0.f};
  f32x4 acc[4][4];
  f32x4 run[4];
#pragma unroll
  for (int mi = 0; mi < 4; ++mi)
#pragma unroll
    for (int ee = 0; ee < 4; ++ee) run[mi][ee] = -1e30f;

  // ---- prologue: stage full A tile (128 x 256) through the 4 subs, read to regs
#pragma unroll
  for (int s = 0; s < 4; ++s)
    STG4(s, qsrcA, s * 64);
  GATE(0); BARR(); SCHED0();

  bf16x8 a[4][8];               // resident A: 4 m-frags x 8 k-frags = 128 VGPR
#pragma unroll
  for (int mi = 0; mi < 4; ++mi) {
    const int rb = (mrow + mi * 16) * 64;
#pragma unroll
    for (int kq = 0; kq < 4; ++kq) {
      a[mi][kq * 2 + 0] = *(const bf16x8*)&lds[kq][rb + pk0];
      a[mi][kq * 2 + 1] = *(const bf16x8*)&lds[kq][rb + (pk0 ^ 32)];
    }
  }
  LGKM0(); BARR();              // all waves done reading A before B overwrites

  // ---- B ring: chunk c staged at phase c-3, GATE(12) = 3 phases x 4 gloads
  const unsigned short* rs = rsrc0;
  STG4(0, rs, 0);
  STG4(1, rs, 64);
  STG4(2, rs, 128);

  for (int bt = 0; bt < NTILES - 1; ++bt) {
    //  CSUB ACM STG SSUB KOFF          GATE
    PH(0,  0,  1,  3,  192,            12);
    PH(1,  1,  1,  0,  32768,          12);
    PH(2,  1,  1,  1,  32768 + 64,     12);
    PH(3,  1,  1,  2,  32768 + 128,    12);
    FOLD();
    rs += 32768;                // next B-tile (128 rows x 256 k)
  }
  // final tile: last stage at its first phase, then drain
  PH(0, 0, 1, 3, 192, 12);
  PH(1, 1, 0, 0, 0,    8);
  PH(2, 1, 0, 0, 0,    4);
  PH(3, 1, 0, 0, 0,    0);
  FOLD();

  // reduce over the 16 column-lanes, one atomic per output row
#pragma unroll
  for (int mi = 0; mi < 4; ++mi)
#pragma unroll
  for (int ee = 0; ee < 4; ++ee) {
    float v = run[mi][ee];
    v = fmaxf(v, __shfl_xor(v, 1));
    v = fmaxf(v, __shfl_xor(v, 2));
    v = fmaxf(v, __shfl_xor(v, 4));
    v = fmaxf(v, __shfl_xor(v, 8));
    if ((lane & 15) == 0)
      atomicMaxFloat(&out[bm * BM2 + wm * 64 + mi * 16 + (lane >> 4) * 4 + ee], v);
  }
}

extern "C" void kernel_launch(void* const* d_in, const int* in_sizes, int n_in,
                              void* d_out, int out_size, void* d_ws, size_t ws_size,
                              hipStream_t stream) {
  const float* refs = (const float*)d_in[0];
  const float* img  = (const float*)d_in[1];
  float* out = (float*)d_out;

  unsigned short* Rb = (unsigned short*)d_ws;                 // 131072*256 bf16 = 64MB
  unsigned short* Qb = Rb + (size_t)NREF * KD;                // 4096*256 bf16 = 2MB

  hipLaunchKernelGGL(norm_kernel, dim3(NNW * HN + HN), dim3(256), 0, stream,
                     refs, img, Rb, Qb, out);
  hipLaunchKernelGGL(simmax_kernel, dim3(NCH * (HW / BM2)), dim3(256), 0, stream,
                     Qb, Rb, out);
}